// Round 1
// baseline (401.095 us; speedup 1.0000x reference)
//
#include <hip/hip_runtime.h>

typedef __bf16  bf16x8 __attribute__((ext_vector_type(8)));
typedef float   f32x16 __attribute__((ext_vector_type(16)));
typedef unsigned short u16;

__device__ __forceinline__ u16 f2bf(float f) {
  union { float f; unsigned u32; } c; c.f = f;
  unsigned r = c.u32 + 0x7fffu + ((c.u32 >> 16) & 1u);   // RNE
  return (u16)(r >> 16);
}
__device__ __forceinline__ float bf2f(u16 u) {
  union { unsigned u32; float f; } c; c.u32 = (unsigned)u << 16; return c.f;
}

// async global->LDS, 16B per lane; HW places lane i at (wave-uniform base)+i*16
__device__ __forceinline__ void async16(const void* g, void* l) {
  __builtin_amdgcn_global_load_lds(
      (const __attribute__((address_space(1))) unsigned*)g,
      (__attribute__((address_space(3))) unsigned*)l, 16, 0, 0);
}

// ---------------- circulant builder: Ct[n*512+k] = w[(n-k)&511] / sqrt(512)
__global__ __launch_bounds__(256) void build_ct(const float* __restrict__ w,
                                                u16* __restrict__ ct) {
  int idx = blockIdx.x * 256 + threadIdx.x;          // 0..262143
  int n = idx >> 9, k = idx & 511;
  float v = w[(n - k) & 511] * 0.04419417382415922f; // 1/sqrt(512)
  ct[idx] = f2bf(v);
}

// ---------------- transpose + cast: out(bf16)[c][r] = in(fp32)[r][c]
__global__ __launch_bounds__(256) void transpose_w(const float* __restrict__ in,
                                                   u16* __restrict__ out,
                                                   int R, int C) {
  __shared__ float tile[32][33];
  int bx = blockIdx.x * 32;
  int by = blockIdx.y * 32;
  int tx = threadIdx.x & 31, ty = threadIdx.x >> 5;
#pragma unroll
  for (int r = ty; r < 32; r += 8)
    tile[r][tx] = in[(size_t)(by + r) * C + bx + tx];
  __syncthreads();
#pragma unroll
  for (int r = ty; r < 32; r += 8)
    out[(size_t)(bx + r) * R + by + tx] = f2bf(tile[tx][r]);
}

// ---------------- LayerNorm [64,512] slab, fp32 in, single global read
__global__ __launch_bounds__(512, 2) void ln_f32(const float* __restrict__ x,
                                                 const float* __restrict__ g,
                                                 const float* __restrict__ beta,
                                                 u16* __restrict__ out) {
  const int tid = threadIdx.x;
  const size_t base = (size_t)blockIdx.x * 32768;
  float4 v[16];
  float s = 0.f, ss = 0.f;
#pragma unroll
  for (int j = 0; j < 16; ++j) {
    v[j] = *(const float4*)(x + base + tid * 4 + j * 2048);
    s  += v[j].x + v[j].y + v[j].z + v[j].w;
    ss += v[j].x * v[j].x + v[j].y * v[j].y + v[j].z * v[j].z + v[j].w * v[j].w;
  }
#pragma unroll
  for (int off = 32; off > 0; off >>= 1) {
    s += __shfl_down(s, off, 64);
    ss += __shfl_down(ss, off, 64);
  }
  __shared__ float red[16];
  int wave = tid >> 6, lane = tid & 63;
  if (lane == 0) { red[wave] = s; red[8 + wave] = ss; }
  __syncthreads();
  float S = 0.f, SS = 0.f;
#pragma unroll
  for (int wv = 0; wv < 8; ++wv) { S += red[wv]; SS += red[8 + wv]; }
  const float inv = 1.0f / 32768.0f;
  float mu = S * inv;
  float rs = rsqrtf(SS * inv - mu * mu + 1e-5f);
#pragma unroll
  for (int j = 0; j < 16; ++j) {
    const int i = tid * 4 + j * 2048;
    float4 gv = *(const float4*)(g + i);
    float4 bv = *(const float4*)(beta + i);
    uint2 o;
    o.x = (unsigned)f2bf((v[j].x - mu) * rs * gv.x + bv.x) |
          ((unsigned)f2bf((v[j].y - mu) * rs * gv.y + bv.y) << 16);
    o.y = (unsigned)f2bf((v[j].z - mu) * rs * gv.z + bv.z) |
          ((unsigned)f2bf((v[j].w - mu) * rs * gv.w + bv.w) << 16);
    *(uint2*)(out + base + i) = o;
  }
}

// ---------------- LayerNorm [64,512] slab, bf16 in, single global read
__global__ __launch_bounds__(512, 2) void ln_bf16(const u16* __restrict__ x,
                                                  const float* __restrict__ g,
                                                  const float* __restrict__ beta,
                                                  u16* __restrict__ out) {
  const int tid = threadIdx.x;
  const size_t base = (size_t)blockIdx.x * 32768;
  uint4 v[8];
  float s = 0.f, ss = 0.f;
#pragma unroll
  for (int j = 0; j < 8; ++j) {
    v[j] = *(const uint4*)(x + base + tid * 8 + j * 4096);
    const unsigned* a = &v[j].x;
#pragma unroll
    for (int t = 0; t < 4; ++t) {
      float lo = bf2f((u16)(a[t] & 0xffff)), hi = bf2f((u16)(a[t] >> 16));
      s += lo + hi; ss += lo * lo + hi * hi;
    }
  }
#pragma unroll
  for (int off = 32; off > 0; off >>= 1) {
    s += __shfl_down(s, off, 64);
    ss += __shfl_down(ss, off, 64);
  }
  __shared__ float red[16];
  int wave = tid >> 6, lane = tid & 63;
  if (lane == 0) { red[wave] = s; red[8 + wave] = ss; }
  __syncthreads();
  float S = 0.f, SS = 0.f;
#pragma unroll
  for (int wv = 0; wv < 8; ++wv) { S += red[wv]; SS += red[8 + wv]; }
  const float inv = 1.0f / 32768.0f;
  float mu = S * inv;
  float rs = rsqrtf(SS * inv - mu * mu + 1e-5f);
#pragma unroll
  for (int j = 0; j < 8; ++j) {
    const int i = tid * 8 + j * 4096;
    const unsigned* a = &v[j].x;
    uint4 o;
    unsigned* ov = &o.x;
#pragma unroll
    for (int t = 0; t < 4; ++t) {
      float lo = bf2f((u16)(a[t] & 0xffff)), hi = bf2f((u16)(a[t] >> 16));
      float glo = g[i + 2 * t], ghi = g[i + 2 * t + 1];
      float blo = beta[i + 2 * t], bhi = beta[i + 2 * t + 1];
      ov[t] = (unsigned)f2bf((lo - mu) * rs * glo + blo) |
              ((unsigned)f2bf((hi - mu) * rs * ghi + bhi) << 16);
    }
    *(uint4*)(out + base + i) = o;
  }
}

// ---------------- GEMM: C[M,N] = A[M,K](bf16) @ Bt[N,K](bf16)^T
// 256x256 block tile, BK=16, 512 threads = 8 waves (2M x 4N), per-wave 128x64.
// mfma_f32_32x32x16_bf16; acc[4][2] f32x16.
// LDS: 4-deep ring of (A 8KB + B 8KB) K-slices = 64KB. Stage K-tile u+2 while
// computing u: the target buffer's last reads finished in window u-2 (>=2
// barriers ago) -> race-free by construction. One counted s_waitcnt vmcnt(2)
// per K-tile (never a full drain in the main loop); raw s_barrier; setprio(1)
// around the MFMA cluster; sched_barrier(0) fences per rule #18.
// Row stride is 32B -> every fragment ds_read_b128 covers a contiguous 1KB
// (one distinct 16B chunk per lane): bank-conflict-free, and staging is
// lane-linear so global_load_lds needs no swizzle on either side.
// MODE 0: plain, bf16 out   MODE 1: +bias, ReLU, bf16 out
// MODE 2: +bias, +resid(fp32), fp32 out
template <int MODE>
__global__ __launch_bounds__(512, 2) void gemm_bt(
    const u16* __restrict__ A, const u16* __restrict__ Bt,
    const float* __restrict__ bias, const float* __restrict__ resid,
    float* __restrict__ Cf, u16* __restrict__ Cb,
    int M, int N, int K, int MT) {
  __shared__ u16 As[16384];   // 4 buffers x 4096 u16 ([256 rows][16 k])
  __shared__ u16 Bs[16384];

  const int tid  = threadIdx.x;
  const int lane = tid & 63;
  const int wave = tid >> 6;
  const int l31  = lane & 31, hi = lane >> 5;
  const int wr = wave >> 2, wc = wave & 3;          // 2 x 4 wave grid

  // bijective XCD-aware block swizzle (m204): consecutive wgid on one XCD
  // share a B panel (256x K bf16, L2-resident)
  const int nwg = gridDim.x;
  const int q = nwg >> 3, r8 = nwg & 7;
  const int xcd = blockIdx.x & 7, loc = blockIdx.x >> 3;
  const int wgid =
      (xcd < r8 ? xcd * (q + 1) : r8 * (q + 1) + (xcd - r8) * q) + loc;
  const int bm = wgid % MT, bn = wgid / MT;
  const int m0 = bm * 256, n0 = bn * 256;
  (void)M;

  // staging: thread t loads 16B = row (t>>1), k-slot (t&1) of the 256x16 slice
  const u16* ag = A  + (size_t)(m0 + (tid >> 1)) * K + (tid & 1) * 8;
  const u16* bg = Bt + (size_t)(n0 + (tid >> 1)) * K + (tid & 1) * 8;

  // fragment read offsets (u16 units): row*16 + (lane>>5)*8, + m*512 / n*512
  const int aoff = (wr * 128 + l31) * 16 + hi * 8;
  const int boff = (wc * 64  + l31) * 16 + hi * 8;

  f32x16 acc[4][2];
#pragma unroll
  for (int m = 0; m < 4; ++m)
#pragma unroll
    for (int n = 0; n < 2; ++n)
#pragma unroll
      for (int i = 0; i < 16; ++i) acc[m][n][i] = 0.f;

  const int NT = K >> 4;        // K-tiles of 16

  // prologue: stage tiles 0 and 1; wait for tile 0 (tile 1 stays in flight)
  async16(ag,      As + tid * 8);
  async16(bg,      Bs + tid * 8);
  async16(ag + 16, As + 4096 + tid * 8);
  async16(bg + 16, Bs + 4096 + tid * 8);
  asm volatile("s_waitcnt vmcnt(2)" ::: "memory");
  __builtin_amdgcn_sched_barrier(0);
  __builtin_amdgcn_s_barrier();

  for (int u = 0; u < NT; ++u) {
    const int bb = (u & 3) * 4096;
    bf16x8 av[4], bv[2];
#pragma unroll
    for (int m = 0; m < 4; ++m)
      av[m] = *(const bf16x8*)&As[bb + aoff + m * 512];
#pragma unroll
    for (int n = 0; n < 2; ++n)
      bv[n] = *(const bf16x8*)&Bs[bb + boff + n * 512];
    if (u + 2 < NT) {                       // stage u+2 into ring slot (u+2)&3
      const int sb = ((u + 2) & 3) * 4096 + tid * 8;
      async16(ag + (size_t)(u + 2) * 16, As + sb);
      async16(bg + (size_t)(u + 2) * 16, Bs + sb);
    }
    __builtin_amdgcn_s_barrier();
    asm volatile("s_waitcnt lgkmcnt(0)" ::: "memory");
    __builtin_amdgcn_sched_barrier(0);
    __builtin_amdgcn_s_setprio(1);
#pragma unroll
    for (int m = 0; m < 4; ++m)
#pragma unroll
      for (int n = 0; n < 2; ++n)
        acc[m][n] = __builtin_amdgcn_mfma_f32_32x32x16_bf16(av[m], bv[n],
                                                            acc[m][n], 0, 0, 0);
    __builtin_amdgcn_s_setprio(0);
    __builtin_amdgcn_sched_barrier(0);
    // counted wait: leave u+2's 2 loads in flight; guarantee u+1 has landed
    if (u + 2 < NT) asm volatile("s_waitcnt vmcnt(2)" ::: "memory");
    else            asm volatile("s_waitcnt vmcnt(0)" ::: "memory");
    __builtin_amdgcn_sched_barrier(0);
    __builtin_amdgcn_s_barrier();
  }

  // epilogue: C/D layout (32x32): col = lane&31, row = (r&3)+8*(r>>2)+4*(lane>>5)
#pragma unroll
  for (int n = 0; n < 2; ++n) {
    const int col = n0 + wc * 64 + n * 32 + l31;
    float bj = 0.f;
    if (MODE >= 1) bj = bias[col];
#pragma unroll
    for (int m = 0; m < 4; ++m) {
      const int row0 = m0 + wr * 128 + m * 32 + hi * 4;
#pragma unroll
      for (int g = 0; g < 4; ++g)
#pragma unroll
        for (int t = 0; t < 4; ++t) {
          float v = acc[m][n][g * 4 + t] + bj;
          if (MODE == 1) v = fmaxf(v, 0.f);
          const size_t idx = (size_t)(row0 + g * 8 + t) * N + col;
          if (MODE == 2) { v += resid[idx]; Cf[idx] = v; }
          else           Cb[idx] = f2bf(v);
        }
    }
  }
}

extern "C" void kernel_launch(void* const* d_in, const int* in_sizes, int n_in,
                              void* d_out, int out_size, void* d_ws,
                              size_t ws_size, hipStream_t stream) {
  const float* x    = (const float*)d_in[0];  // [512,64,512] fp32
  const float* w    = (const float*)d_in[1];  // [1,512]
  const float* ln1w = (const float*)d_in[2];  // [64,512]
  const float* ln1b = (const float*)d_in[3];
  const float* ln2w = (const float*)d_in[4];
  const float* ln2b = (const float*)d_in[5];
  const float* w1   = (const float*)d_in[6];  // [512,2048]
  const float* b1   = (const float*)d_in[7];  // [2048]
  const float* w2   = (const float*)d_in[8];  // [2048,512]
  const float* b2   = (const float*)d_in[9];  // [512]
  float* out = (float*)d_out;                 // [512,64,512] fp32

  char* ws = (char*)d_ws;
  // y overlaps h1+h2 (both dead before FFN1 writes y)
  u16*   y   = (u16*)(ws);                  // [32768,2048] bf16  134,217,728 B @ 0
  u16*   h1  = (u16*)(ws);                  // [32768,512]  bf16   33,554,432 B @ 0
  u16*   h2  = (u16*)(ws + 33554432);       // [32768,512]  bf16   33,554,432 B
  u16*   h3  = (u16*)(ws + 134217728);      // [32768,512]  bf16   33,554,432 B
  u16*   ct  = (u16*)(ws + 167772160);      // [512,512]    bf16      524,288 B
  u16*   w1t = (u16*)(ws + 168296448);      // [2048,512]   bf16    2,097,152 B
  u16*   w2t = (u16*)(ws + 170393600);      // [512,2048]   bf16    2,097,152 B
  // peak ws use: 172,490,752 B

  build_ct<<<1024, 256, 0, stream>>>(w, ct);
  transpose_w<<<dim3(64, 16), 256, 0, stream>>>(w1, w1t, 512, 2048);
  transpose_w<<<dim3(16, 64), 256, 0, stream>>>(w2, w2t, 2048, 512);

  // LN1: x(fp32) -> h1(bf16), single global read
  ln_f32<<<512, 512, 0, stream>>>(x, ln1w, ln1b, h1);
  // freq filter: h2(bf16) = h1 @ C   (M=32768, N=512, K=512) -> 256 blocks
  gemm_bt<0><<<256, 512, 0, stream>>>(h1, ct, nullptr, nullptr,
                                      nullptr, h2, 32768, 512, 512, 128);
  // LN2: h2(bf16) -> h3(bf16)
  ln_bf16<<<512, 512, 0, stream>>>(h2, ln2w, ln2b, h3);
  // FFN1: y(bf16) = relu(h3 @ w1 + b1)  (N=2048) -> 1024 blocks
  gemm_bt<1><<<1024, 512, 0, stream>>>(h3, w1t, b1, nullptr,
                                       nullptr, y, 32768, 2048, 512, 128);
  // FFN2 + residual: out(fp32) = y @ w2 + b2 + x  (K=2048) -> 256 blocks
  gemm_bt<2><<<256, 512, 0, stream>>>(y, w2t, b2, x,
                                      out, nullptr, 32768, 512, 2048, 128);
}

// Round 3
// 400.516 us; speedup vs baseline: 1.0014x; 1.0014x over previous
//
#include <hip/hip_runtime.h>

typedef __bf16  bf16x8 __attribute__((ext_vector_type(8)));
typedef float   f32x4  __attribute__((ext_vector_type(4)));
typedef unsigned short u16;

__device__ __forceinline__ u16 f2bf(float f) {
  union { float f; unsigned u32; } c; c.f = f;
  unsigned r = c.u32 + 0x7fffu + ((c.u32 >> 16) & 1u);   // RNE
  return (u16)(r >> 16);
}
__device__ __forceinline__ float bf2f(u16 u) {
  union { unsigned u32; float f; } c; c.u32 = (unsigned)u << 16; return c.f;
}

// async global->LDS, 16B per lane; HW places lane i at (wave-uniform base)+i*16
__device__ __forceinline__ void async16(const void* g, void* l) {
  __builtin_amdgcn_global_load_lds(
      (const __attribute__((address_space(1))) unsigned*)g,
      (__attribute__((address_space(3))) unsigned*)l, 16, 0, 0);
}

// ---------------- circulant builder: Ct[n*512+k] = w[(n-k)&511] / sqrt(512)
__global__ __launch_bounds__(256) void build_ct(const float* __restrict__ w,
                                                u16* __restrict__ ct) {
  int idx = blockIdx.x * 256 + threadIdx.x;          // 0..262143
  int n = idx >> 9, k = idx & 511;
  float v = w[(n - k) & 511] * 0.04419417382415922f; // 1/sqrt(512)
  ct[idx] = f2bf(v);
}

// ---------------- transpose + cast: out(bf16)[c][r] = in(fp32)[r][c]
__global__ __launch_bounds__(256) void transpose_w(const float* __restrict__ in,
                                                   u16* __restrict__ out,
                                                   int R, int C) {
  __shared__ float tile[32][33];
  int bx = blockIdx.x * 32;
  int by = blockIdx.y * 32;
  int tx = threadIdx.x & 31, ty = threadIdx.x >> 5;
#pragma unroll
  for (int r = ty; r < 32; r += 8)
    tile[r][tx] = in[(size_t)(by + r) * C + bx + tx];
  __syncthreads();
#pragma unroll
  for (int r = ty; r < 32; r += 8)
    out[(size_t)(bx + r) * R + by + tx] = f2bf(tile[tx][r]);
}

// ---------------- LayerNorm [64,512] slab, fp32 in, single global read
__global__ __launch_bounds__(512, 2) void ln_f32(const float* __restrict__ x,
                                                 const float* __restrict__ g,
                                                 const float* __restrict__ beta,
                                                 u16* __restrict__ out) {
  const int tid = threadIdx.x;
  const size_t base = (size_t)blockIdx.x * 32768;
  float4 v[16];
  float s = 0.f, ss = 0.f;
#pragma unroll
  for (int j = 0; j < 16; ++j) {
    v[j] = *(const float4*)(x + base + tid * 4 + j * 2048);
    s  += v[j].x + v[j].y + v[j].z + v[j].w;
    ss += v[j].x * v[j].x + v[j].y * v[j].y + v[j].z * v[j].z + v[j].w * v[j].w;
  }
#pragma unroll
  for (int off = 32; off > 0; off >>= 1) {
    s += __shfl_down(s, off, 64);
    ss += __shfl_down(ss, off, 64);
  }
  __shared__ float red[16];
  int wave = tid >> 6, lane = tid & 63;
  if (lane == 0) { red[wave] = s; red[8 + wave] = ss; }
  __syncthreads();
  float S = 0.f, SS = 0.f;
#pragma unroll
  for (int wv = 0; wv < 8; ++wv) { S += red[wv]; SS += red[8 + wv]; }
  const float inv = 1.0f / 32768.0f;
  float mu = S * inv;
  float rs = rsqrtf(SS * inv - mu * mu + 1e-5f);
#pragma unroll
  for (int j = 0; j < 16; ++j) {
    const int i = tid * 4 + j * 2048;
    float4 gv = *(const float4*)(g + i);
    float4 bv = *(const float4*)(beta + i);
    uint2 o;
    o.x = (unsigned)f2bf((v[j].x - mu) * rs * gv.x + bv.x) |
          ((unsigned)f2bf((v[j].y - mu) * rs * gv.y + bv.y) << 16);
    o.y = (unsigned)f2bf((v[j].z - mu) * rs * gv.z + bv.z) |
          ((unsigned)f2bf((v[j].w - mu) * rs * gv.w + bv.w) << 16);
    *(uint2*)(out + base + i) = o;
  }
}

// ---------------- LayerNorm [64,512] slab, bf16 in, single global read
__global__ __launch_bounds__(512, 2) void ln_bf16(const u16* __restrict__ x,
                                                  const float* __restrict__ g,
                                                  const float* __restrict__ beta,
                                                  u16* __restrict__ out) {
  const int tid = threadIdx.x;
  const size_t base = (size_t)blockIdx.x * 32768;
  uint4 v[8];
  float s = 0.f, ss = 0.f;
#pragma unroll
  for (int j = 0; j < 8; ++j) {
    v[j] = *(const uint4*)(x + base + tid * 8 + j * 4096);
    const unsigned* a = &v[j].x;
#pragma unroll
    for (int t = 0; t < 4; ++t) {
      float lo = bf2f((u16)(a[t] & 0xffff)), hi = bf2f((u16)(a[t] >> 16));
      s += lo + hi; ss += lo * lo + hi * hi;
    }
  }
#pragma unroll
  for (int off = 32; off > 0; off >>= 1) {
    s += __shfl_down(s, off, 64);
    ss += __shfl_down(ss, off, 64);
  }
  __shared__ float red[16];
  int wave = tid >> 6, lane = tid & 63;
  if (lane == 0) { red[wave] = s; red[8 + wave] = ss; }
  __syncthreads();
  float S = 0.f, SS = 0.f;
#pragma unroll
  for (int wv = 0; wv < 8; ++wv) { S += red[wv]; SS += red[8 + wv]; }
  const float inv = 1.0f / 32768.0f;
  float mu = S * inv;
  float rs = rsqrtf(SS * inv - mu * mu + 1e-5f);
#pragma unroll
  for (int j = 0; j < 8; ++j) {
    const int i = tid * 8 + j * 4096;
    const unsigned* a = &v[j].x;
    uint4 o;
    unsigned* ov = &o.x;
#pragma unroll
    for (int t = 0; t < 4; ++t) {
      float lo = bf2f((u16)(a[t] & 0xffff)), hi = bf2f((u16)(a[t] >> 16));
      float glo = g[i + 2 * t], ghi = g[i + 2 * t + 1];
      float blo = beta[i + 2 * t], bhi = beta[i + 2 * t + 1];
      ov[t] = (unsigned)f2bf((lo - mu) * rs * glo + blo) |
              ((unsigned)f2bf((hi - mu) * rs * ghi + bhi) << 16);
    }
    *(uint4*)(out + base + i) = o;
  }
}

// ---------------- GEMM: C[M,N] = A[M,K](bf16) @ Bt[N,K](bf16)^T
// 256x256 tile, BK=64, 512 thr = 8 waves (2M x 4N), per-wave 128x64,
// mfma_f32_16x16x32_bf16, acc[8][4] f32x4.
// LDS 128KB: A,B each 2buf x [256][64] u16, linear row map (LDS row r <->
// tile row r) with chunk swizzle: 16B slot s of row r holds global chunk
// s^(r&7) -> every 8-lane group of a ds_read_b128 is a slot permutation,
// 0 bank conflicts (verified round 0). row&7 == l16&7 on all fragment rows.
// 4 phases/K-tile (one output quadrant each, 16 MFMA); stage units (2
// async16/thread) in first-use order: ph0->A-qm0(t+1), ph1->B-qn0(t+1),
// ph2->B-qn1(t+1), ph3->A-qm1(t+1). Derived waits (queue sim): vmcnt(4) at
// ends of phases 0,1,3; none at 2; never drains in steady state. lgkmcnt(0)
// drained before each MFMA cluster and hence before each phase barrier ->
// tile-boundary barriers guarantee all prior-tile ds_reads completed before
// the buffer is overwritten (race-free).
// MODE 0: plain, bf16 out   MODE 1: +bias, ReLU, bf16 out
// MODE 2: +bias, +resid(fp32), fp32 out
template <int MODE>
__global__ __launch_bounds__(512, 2) void gemm_bt(
    const u16* __restrict__ A, const u16* __restrict__ Bt,
    const float* __restrict__ bias, const float* __restrict__ resid,
    float* __restrict__ Cf, u16* __restrict__ Cb,
    int M, int N, int K, int MT) {
  __shared__ u16 As[32768];   // 2 x [256][64]
  __shared__ u16 Bs[32768];

  const int tid  = threadIdx.x;
  const int lane = tid & 63;
  const int wave = tid >> 6;
  const int l16  = lane & 15, quad = lane >> 4;
  const int wr = wave >> 2, wc = wave & 3;          // 2M x 4N wave grid

  // bijective XCD-aware block swizzle (m204): consecutive wgid on one XCD
  // share bn (B panel stays L2-resident)
  const int nwg = gridDim.x;
  const int q8 = nwg >> 3, r8 = nwg & 7;
  const int xcd = blockIdx.x & 7, loc = blockIdx.x >> 3;
  const int wgid =
      (xcd < r8 ? xcd * (q8 + 1) : r8 * (q8 + 1) + (xcd - r8) * q8) + loc;
  const int bm = wgid % MT, bn = wgid / MT;
  const int m0 = bm * 256, n0 = bn * 256;
  (void)M;

  // ---- staging geometry (lane-linear dests; source pre-swizzled) ----
  const int srow   = tid >> 3;                       // 0..63
  const int grp    = tid >> 8;                       // 0..1
  const int srow32 = srow & 31;                      // 0..31
  const int gch    = ((tid & 7) ^ (srow & 7)) * 8;   // swizzled chunk (u16)
  const u16* agb = A  + (size_t)(m0 + srow) * K + gch;
  const u16* bgb = Bt + (size_t)(n0 + grp * 64 + srow32) * K + gch;
  const int adst = tid * 8;                          // == srow*64 + slot*8
  const int bdst = grp * 4096 + (tid & 255) * 8;     // == row*64 + slot*8

  // A-unit qm: rows qm*64+[0,64) and qm*64+128+[0,64)  -> LDS qm*4096 (+8192)
#define STAGE_A(t1, qm) {                                                   \
    const u16* g_ = agb + (size_t)(qm) * 64 * K + (t1) * 64;                \
    u16* d_ = As + (((t1) & 1) << 14) + (qm) * 4096 + adst;                 \
    async16(g_, d_);                                                        \
    async16(g_ + (size_t)128 * K, d_ + 8192); }
  // B-unit qn: rows grp*64+qn*32+[0,32) and +128      -> LDS qn*2048 (+8192)
#define STAGE_B(t1, qn) {                                                   \
    const u16* g_ = bgb + (size_t)(qn) * 32 * K + (t1) * 64;                \
    u16* d_ = Bs + (((t1) & 1) << 14) + (qn) * 2048 + bdst;                 \
    async16(g_, d_);                                                        \
    async16(g_ + (size_t)128 * K, d_ + 8192); }

  // ---- fragment read offsets (u16 units); row = wr*128+qm*64+m*16+l16 etc.
  const int arow = wr * 8192 + l16 * 64;
  const int brow = wc * 4096 + l16 * 64;
  const int sw0 = ((0 + quad) ^ (l16 & 7)) * 8;      // k-chunks 0..3
  const int sw1 = ((4 + quad) ^ (l16 & 7)) * 8;      // k-chunks 4..7

  bf16x8 av[4][2], bv[2][2][2];
  f32x4 acc[8][4];
#pragma unroll
  for (int i = 0; i < 8; ++i)
#pragma unroll
    for (int j = 0; j < 4; ++j) acc[i][j] = (f32x4){0.f, 0.f, 0.f, 0.f};

#define LDA(qm) {                                                           \
    const int ab = (buf << 14) + (qm) * 4096 + arow;                        \
    _Pragma("unroll")                                                       \
    for (int m_ = 0; m_ < 4; ++m_) {                                        \
      av[m_][0] = *(const bf16x8*)&As[ab + m_ * 1024 + sw0];                \
      av[m_][1] = *(const bf16x8*)&As[ab + m_ * 1024 + sw1];                \
    } }
#define LDB(qn) {                                                           \
    const int bb = (buf << 14) + (qn) * 2048 + brow;                        \
    _Pragma("unroll")                                                       \
    for (int n_ = 0; n_ < 2; ++n_) {                                        \
      bv[qn][n_][0] = *(const bf16x8*)&Bs[bb + n_ * 1024 + sw0];            \
      bv[qn][n_][1] = *(const bf16x8*)&Bs[bb + n_ * 1024 + sw1];            \
    } }
#define MFMA_Q(qm, qn)                                                      \
    __builtin_amdgcn_s_setprio(1);                                          \
    _Pragma("unroll")                                                       \
    for (int m_ = 0; m_ < 4; ++m_) {                                        \
      _Pragma("unroll")                                                     \
      for (int n_ = 0; n_ < 2; ++n_) {                                      \
        acc[(qm)*4+m_][(qn)*2+n_] = __builtin_amdgcn_mfma_f32_16x16x32_bf16(\
            av[m_][0], bv[qn][n_][0], acc[(qm)*4+m_][(qn)*2+n_], 0, 0, 0);  \
        acc[(qm)*4+m_][(qn)*2+n_] = __builtin_amdgcn_mfma_f32_16x16x32_bf16(\
            av[m_][1], bv[qn][n_][1], acc[(qm)*4+m_][(qn)*2+n_], 0, 0, 0);  \
      } }                                                                   \
    __builtin_amdgcn_s_setprio(0);

#define SB    __builtin_amdgcn_sched_barrier(0)
#define BAR   __builtin_amdgcn_s_barrier()
#define LGKM0 asm volatile("s_waitcnt lgkmcnt(0)" ::: "memory")
#define VM(n) asm volatile("s_waitcnt vmcnt(" #n ")" ::: "memory")

  const int NT = K >> 6;        // K-tiles of 64

  // prologue: stage tile 0 in first-use order; wait A0,B0; barrier
  STAGE_A(0, 0); STAGE_B(0, 0); STAGE_B(0, 1); STAGE_A(0, 1);
  VM(4);
  SB; BAR;

  for (int t = 0; t < NT; ++t) {
    const int buf = t & 1;
    const bool more = (t + 1) < NT;
    // ---- phase 0 : quadrant (qm0,qn0); stage A-qm0(t+1)
    LDA(0); LDB(0);
    if (more) STAGE_A(t + 1, 0);
    BAR; LGKM0; SB;
    MFMA_Q(0, 0);
    SB;
    if (more) VM(4); else VM(2);      // B-qn1(t) landed
    SB; BAR;
    // ---- phase 1 : quadrant (qm0,qn1); stage B-qn0(t+1)
    LDB(1);
    if (more) STAGE_B(t + 1, 0);
    BAR; LGKM0; SB;
    MFMA_Q(0, 1);
    SB;
    if (more) VM(4); else VM(0);      // A-qm1(t) landed
    SB; BAR;
    // ---- phase 2 : quadrant (qm1,qn0); stage B-qn1(t+1)
    LDA(1);
    if (more) STAGE_B(t + 1, 1);
    BAR; LGKM0; SB;
    MFMA_Q(1, 0);
    SB; BAR;                          // no wait needed (ph3 reads nothing)
    // ---- phase 3 : quadrant (qm1,qn1); stage A-qm1(t+1)
    if (more) STAGE_A(t + 1, 1);
    BAR; SB;
    MFMA_Q(1, 1);
    SB;
    if (more) VM(4);                  // A-qm0(t+1), B-qn0(t+1) landed
    SB; BAR;
  }

#undef STAGE_A
#undef STAGE_B
#undef LDA
#undef LDB
#undef MFMA_Q
#undef SB
#undef BAR
#undef LGKM0
#undef VM

  // epilogue: 16x16x32 C/D layout: col = lane&15, row = (lane>>4)*4 + reg
#pragma unroll
  for (int qn = 0; qn < 2; ++qn)
#pragma unroll
    for (int n = 0; n < 2; ++n) {
      const int col = n0 + wc * 64 + qn * 32 + n * 16 + l16;
      float bj = 0.f;
      if (MODE >= 1) bj = bias[col];
#pragma unroll
      for (int qm = 0; qm < 2; ++qm)
#pragma unroll
        for (int m = 0; m < 4; ++m) {
          const int row0 = m0 + wr * 128 + qm * 64 + m * 16 + quad * 4;
          f32x4 a = acc[qm * 4 + m][qn * 2 + n];
#pragma unroll
          for (int r = 0; r < 4; ++r) {
            float v = a[r] + bj;
            if (MODE == 1) v = fmaxf(v, 0.f);
            const size_t idx = (size_t)(row0 + r) * N + col;
            if (MODE == 2) { v += resid[idx]; Cf[idx] = v; }
            else           Cb[idx] = f2bf(v);
          }
        }
    }
}

extern "C" void kernel_launch(void* const* d_in, const int* in_sizes, int n_in,
                              void* d_out, int out_size, void* d_ws,
                              size_t ws_size, hipStream_t stream) {
  const float* x    = (const float*)d_in[0];  // [512,64,512] fp32
  const float* w    = (const float*)d_in[1];  // [1,512]
  const float* ln1w = (const float*)d_in[2];  // [64,512]
  const float* ln1b = (const float*)d_in[3];
  const float* ln2w = (const float*)d_in[4];
  const float* ln2b = (const float*)d_in[5];
  const float* w1   = (const float*)d_in[6];  // [512,2048]
  const float* b1   = (const float*)d_in[7];  // [2048]
  const float* w2   = (const float*)d_in[8];  // [2048,512]
  const float* b2   = (const float*)d_in[9];  // [512]
  float* out = (float*)d_out;                 // [512,64,512] fp32

  char* ws = (char*)d_ws;
  // y overlaps h1+h2 (both dead before FFN1 writes y)
  u16*   y   = (u16*)(ws);                  // [32768,2048] bf16  134,217,728 B @ 0
  u16*   h1  = (u16*)(ws);                  // [32768,512]  bf16   33,554,432 B @ 0
  u16*   h2  = (u16*)(ws + 33554432);       // [32768,512]  bf16   33,554,432 B
  u16*   h3  = (u16*)(ws + 134217728);      // [32768,512]  bf16   33,554,432 B
  u16*   ct  = (u16*)(ws + 167772160);      // [512,512]    bf16      524,288 B
  u16*   w1t = (u16*)(ws + 168296448);      // [2048,512]   bf16    2,097,152 B
  u16*   w2t = (u16*)(ws + 170393600);      // [512,2048]   bf16    2,097,152 B
  // peak ws use: 172,490,752 B

  build_ct<<<1024, 256, 0, stream>>>(w, ct);
  transpose_w<<<dim3(64, 16), 256, 0, stream>>>(w1, w1t, 512, 2048);
  transpose_w<<<dim3(16, 64), 256, 0, stream>>>(w2, w2t, 2048, 512);

  // LN1: x(fp32) -> h1(bf16), single global read
  ln_f32<<<512, 512, 0, stream>>>(x, ln1w, ln1b, h1);
  // freq filter: h2(bf16) = h1 @ C   (M=32768, N=512, K=512) -> 256 blocks
  gemm_bt<0><<<256, 512, 0, stream>>>(h1, ct, nullptr, nullptr,
                                      nullptr, h2, 32768, 512, 512, 128);
  // LN2: h2(bf16) -> h3(bf16)
  ln_bf16<<<512, 512, 0, stream>>>(h2, ln2w, ln2b, h3);
  // FFN1: y(bf16) = relu(h3 @ w1 + b1)  (N=2048) -> 1024 blocks
  gemm_bt<1><<<1024, 512, 0, stream>>>(h3, w1t, b1, nullptr,
                                       nullptr, y, 32768, 2048, 512, 128);
  // FFN2 + residual: out(fp32) = y @ w2 + b2 + x  (K=2048) -> 256 blocks
  gemm_bt<2><<<256, 512, 0, stream>>>(y, w2t, b2, x,
                                      out, nullptr, 32768, 512, 2048, 128);
}